// Round 14
// baseline (981.108 us; speedup 1.0000x reference)
//
#include <hip/hip_runtime.h>

typedef short short8 __attribute__((ext_vector_type(8)));
typedef float f32x4 __attribute__((ext_vector_type(4)));

#define DEV static __device__ __forceinline__

DEV unsigned short f2bf(float f) {
  union { float f; unsigned u; } v; v.f = f;
  unsigned u = v.u;
  unsigned r = u + 0x7fffu + ((u >> 16) & 1u);
  return (unsigned short)(r >> 16);
}
DEV float bf2f(unsigned short b) {
  union { unsigned u; float f; } v; v.u = ((unsigned)b) << 16;
  return v.f;
}
DEV void load_lds16(const void* g, void* l) {
  __builtin_amdgcn_global_load_lds(
      (const __attribute__((address_space(1))) unsigned int*)g,
      (__attribute__((address_space(3))) unsigned int*)l, 16, 0, 0);
}
// Bank swizzle for [row][64B] tiles, involution. Verified R3: 0 conflicts.
DEV int swz(int L) { return L ^ ((L >> 3) & 0x30); }

// ---------------- mod = silu(vec) @ mod_w + mod_b -----------------
__global__ __launch_bounds__(256) void zero_mod(const float* __restrict__ b, float* __restrict__ out) {
  int j = blockIdx.x * 256 + threadIdx.x;
  out[j] = b[j];
}

__global__ __launch_bounds__(256) void mod_gemv(const float* __restrict__ vec,
                                                const float* __restrict__ W,
                                                float* __restrict__ out) {
  __shared__ float sv[192];
  int tid = threadIdx.x;
  int kb = blockIdx.y * 192;
  if (tid < 192) {
    float x = vec[kb + tid];
    sv[tid] = x / (1.f + __expf(-x));
  }
  __syncthreads();
  int j = blockIdx.x * 256 + tid;
  float a0 = 0, a1 = 0, a2 = 0, a3 = 0;
  for (int i = 0; i < 192; i += 4) {
    a0 += sv[i + 0] * W[(size_t)(kb + i + 0) * 18432 + j];
    a1 += sv[i + 1] * W[(size_t)(kb + i + 1) * 18432 + j];
    a2 += sv[i + 2] * W[(size_t)(kb + i + 2) * 18432 + j];
    a3 += sv[i + 3] * W[(size_t)(kb + i + 3) * 18432 + j];
  }
  atomicAdd(&out[j], a0 + a1 + a2 + a3);
}

// ---------------- LayerNorm + modulate -> bf16 -----------------
__global__ __launch_bounds__(256) void ln_kernel(const float* __restrict__ in,
                                                 const float* __restrict__ mod,
                                                 int shift_off, int scale_off,
                                                 unsigned short* __restrict__ out) {
  int rowb = blockIdx.x;
  const float* x = in + (size_t)rowb * 3072;
  int tid = threadIdx.x;
  float s = 0.f, ss = 0.f;
  float4 v[3];
#pragma unroll
  for (int r = 0; r < 3; r++) {
    v[r] = *(const float4*)&x[r * 1024 + tid * 4];
    s += v[r].x + v[r].y + v[r].z + v[r].w;
    ss += v[r].x * v[r].x + v[r].y * v[r].y + v[r].z * v[r].z + v[r].w * v[r].w;
  }
#pragma unroll
  for (int m = 32; m; m >>= 1) { s += __shfl_xor(s, m); ss += __shfl_xor(ss, m); }
  __shared__ float red[8];
  int w = tid >> 6, lane = tid & 63;
  if (lane == 0) { red[w] = s; red[4 + w] = ss; }
  __syncthreads();
  s = red[0] + red[1] + red[2] + red[3];
  ss = red[4] + red[5] + red[6] + red[7];
  float mean = s * (1.f / 3072.f);
  float var = ss * (1.f / 3072.f) - mean * mean;
  float rstd = rsqrtf(var + 1e-6f);
#pragma unroll
  for (int r = 0; r < 3; r++) {
    int c = r * 1024 + tid * 4;
    float xv[4] = {v[r].x, v[r].y, v[r].z, v[r].w};
#pragma unroll
    for (int i = 0; i < 4; i++) {
      float o = (xv[i] - mean) * rstd * (1.f + mod[scale_off + c + i]) + mod[shift_off + c + i];
      out[(size_t)rowb * 3072 + c + i] = f2bf(o);
    }
  }
}

// ---------------- transpose fp32 [K][N] -> bf16 [N][K] -----------------
__global__ __launch_bounds__(256) void transpose_k(const float* __restrict__ src,
                                                   unsigned short* __restrict__ dst,
                                                   int K, int N) {
  __shared__ float t[64][65];
  int n0 = blockIdx.x * 64, k0 = blockIdx.y * 64;
  int tid = threadIdx.x;
#pragma unroll
  for (int i = 0; i < 16; i++) {
    int lin = i * 256 + tid;
    int r = lin >> 6, c = lin & 63;
    t[r][c] = src[(size_t)(k0 + r) * N + n0 + c];
  }
  __syncthreads();
#pragma unroll
  for (int i = 0; i < 16; i++) {
    int lin = i * 256 + tid;
    int rn = lin >> 6, cn = lin & 63;
    dst[(size_t)(n0 + rn) * K + k0 + cn] = f2bf(t[cn][rn]);
  }
}

// ---- V transpose: vt[h][d=128][kv=2304] from qkvb (img V) + v_txt ----
__global__ __launch_bounds__(256) void vt_k(const unsigned short* __restrict__ qkvb,
                                            const float* __restrict__ v_txt,
                                            unsigned short* __restrict__ vt) {
  int h = blockIdx.y;
  int c8 = blockIdx.x * 2 + (threadIdx.x >> 7);  // 0..287 kv-chunk
  int d = threadIdx.x & 127;
  int kvb = c8 * 8;
  short8 o;
  if (kvb < 2048) {
#pragma unroll
    for (int j = 0; j < 8; j++)
      o[j] = (short)qkvb[(size_t)(kvb + j) * 9216 + 6144 + h * 128 + d];
  } else {
#pragma unroll
    for (int j = 0; j < 8; j++)
      o[j] = (short)f2bf(v_txt[((size_t)(kvb + j - 2048) * 24 + h) * 128 + d]);
  }
  *(short8*)&vt[((size_t)h * 128 + d) * 2304 + kvb] = o;
}

// ======== 256x256 GEMM, BK=64, dbuf-2, 4-phase-per-tile (m201 8-phase port) ====
// Per tile: 4 phases {ds_read quad-frags | stage 1 half-tile -> barrier ->
// lgkmcnt(0) -> setprio(1) 16 MFMA setprio(0) -> barrier}, quadrant order
// r0c0,r0c1,r1c0,r1c1. Stagger ledger: tile t stages A1(t+1)@p1, B0(t+1)@p2,
// B1(t+1)@p3, A0(t+2)@p4; end-of-tile s_waitcnt vmcnt(2) (vmcnt(0) at NT-2).
// Swizzle: row r of 128B, chunk c at c^(r&7) (involution; verified R9, 0 conf).
template <int EPI>
__global__ __launch_bounds__(512, 2) void gemm8(const unsigned short* __restrict__ A,
                                                const unsigned short* __restrict__ Bt,
                                                const float* __restrict__ bias,
                                                unsigned short* __restrict__ outb,
                                                int N, int ldk, int klen, size_t zstride) {
  __shared__ unsigned short As[2][16384];  // [buf][256 rows][64 k] 32KB each
  __shared__ unsigned short Bs[2][16384];
  const int tid = threadIdx.x, lane = tid & 63, w = tid >> 6;
  const int wr = w >> 2, wc = w & 3;          // 2 x 4 waves, per-wave 128x64
  const int lr = lane & 15, lk = lane >> 4;

  const int bm = blockIdx.y * 256, bn = blockIdx.x * 256;
  const int kbase = blockIdx.z * klen;
  const int NT = klen >> 6;

  // staging: per thread 2x16B per half-tile (128 rows x 64k = 16KB)
  const int j0 = tid * 16, j1 = 8192 + tid * 16;   // byte offsets within a half
  const int r0 = j0 >> 7, r1 = j1 >> 7;            // rows 0..127 within half
  const int sw0 = ((j0 >> 4) & 7) ^ (r0 & 7);
  const int sw1 = ((j1 >> 4) & 7) ^ (r1 & 7);
  const unsigned short* sA0[2] = {A + (size_t)(bm + r0) * ldk + kbase + sw0 * 8,
                                  A + (size_t)(bm + r1) * ldk + kbase + sw1 * 8};
  const unsigned short* sA1[2] = {A + (size_t)(bm + 128 + r0) * ldk + kbase + sw0 * 8,
                                  A + (size_t)(bm + 128 + r1) * ldk + kbase + sw1 * 8};
  const unsigned short* sB0[2] = {Bt + (size_t)(bn + r0) * ldk + kbase + sw0 * 8,
                                  Bt + (size_t)(bn + r1) * ldk + kbase + sw1 * 8};
  const unsigned short* sB1[2] = {Bt + (size_t)(bn + 128 + r0) * ldk + kbase + sw0 * 8,
                                  Bt + (size_t)(bn + 128 + r1) * ldk + kbase + sw1 * 8};

#define STG(SRC, BASE, HALF, KO)                                          \
  do {                                                                    \
    load_lds16(SRC[0] + (KO), (char*)(BASE) + (HALF) * 16384 + j0);       \
    load_lds16(SRC[1] + (KO), (char*)(BASE) + (HALF) * 16384 + j1);       \
  } while (0)

  // fragment read offsets (kk=0); kk=1 = offset ^ 64
  int aoff[8], boff[4];
#pragma unroll
  for (int mi = 0; mi < 8; mi++) {
    int r = wr * 128 + mi * 16 + lr;
    aoff[mi] = r * 128 + ((lk ^ (r & 7)) << 4);
  }
#pragma unroll
  for (int ni = 0; ni < 4; ni++) {
    int r = wc * 64 + ni * 16 + lr;
    boff[ni] = r * 128 + ((lk ^ (r & 7)) << 4);
  }

  f32x4 acc[8][4];
#pragma unroll
  for (int i = 0; i < 8; i++)
#pragma unroll
    for (int j = 0; j < 4; j++) acc[i][j] = (f32x4){0.f, 0.f, 0.f, 0.f};

  // prologue: tile0 complete + A0(1); issue order matters (A0(1) last)
  STG(sA0, As[0], 0, 0);
  STG(sA1, As[0], 1, 0);
  STG(sB0, Bs[0], 0, 0);
  STG(sB1, Bs[0], 1, 0);
  if (1 < NT) STG(sA0, As[1], 0, 64);
  asm volatile("s_waitcnt vmcnt(2)" ::: "memory");
  __builtin_amdgcn_sched_barrier(0);
  __builtin_amdgcn_s_barrier();

  for (int t = 0; t < NT; ++t) {
    const int cb = t & 1, nb = cb ^ 1;
    char* Ab = (char*)As + cb * 32768;
    char* Bb = (char*)Bs + cb * 32768;
    const int k1 = (t + 1) * 64, k2 = (t + 2) * 64;

    short8 aq[4][2], bq[4][2];
    // ---- phase 1: read A-r0 (8) + B-c0 (4); stage A1(t+1); MFMA r0c0
#pragma unroll
    for (int mi = 0; mi < 4; mi++) {
      aq[mi][0] = *(const short8*)(Ab + aoff[mi]);
      aq[mi][1] = *(const short8*)(Ab + (aoff[mi] ^ 64));
    }
#pragma unroll
    for (int ni = 0; ni < 2; ni++) {
      bq[ni][0] = *(const short8*)(Bb + boff[ni]);
      bq[ni][1] = *(const short8*)(Bb + (boff[ni] ^ 64));
    }
    if (t + 1 < NT) STG(sA1, As[nb], 1, k1);
    __builtin_amdgcn_s_barrier();
    asm volatile("s_waitcnt lgkmcnt(0)" ::: "memory");
    __builtin_amdgcn_sched_barrier(0);
    __builtin_amdgcn_s_setprio(1);
#pragma unroll
    for (int mi = 0; mi < 4; mi++)
#pragma unroll
      for (int ni = 0; ni < 2; ni++)
#pragma unroll
        for (int kk = 0; kk < 2; kk++)
          acc[mi][ni] = __builtin_amdgcn_mfma_f32_16x16x32_bf16(aq[mi][kk], bq[ni][kk], acc[mi][ni], 0, 0, 0);
    __builtin_amdgcn_s_setprio(0);
    __builtin_amdgcn_s_barrier();

    // ---- phase 2: read B-c1 (4); stage B0(t+1); MFMA r0c1
#pragma unroll
    for (int ni = 2; ni < 4; ni++) {
      bq[ni][0] = *(const short8*)(Bb + boff[ni]);
      bq[ni][1] = *(const short8*)(Bb + (boff[ni] ^ 64));
    }
    if (t + 1 < NT) STG(sB0, Bs[nb], 0, k1);
    __builtin_amdgcn_s_barrier();
    asm volatile("s_waitcnt lgkmcnt(0)" ::: "memory");
    __builtin_amdgcn_sched_barrier(0);
    __builtin_amdgcn_s_setprio(1);
#pragma unroll
    for (int mi = 0; mi < 4; mi++)
#pragma unroll
      for (int ni = 2; ni < 4; ni++)
#pragma unroll
        for (int kk = 0; kk < 2; kk++)
          acc[mi][ni] = __builtin_amdgcn_mfma_f32_16x16x32_bf16(aq[mi][kk], bq[ni][kk], acc[mi][ni], 0, 0, 0);
    __builtin_amdgcn_s_setprio(0);
    __builtin_amdgcn_s_barrier();

    // ---- phase 3: read A-r1 (8, overwrite aq); stage B1(t+1); MFMA r1c0
#pragma unroll
    for (int mi = 0; mi < 4; mi++) {
      aq[mi][0] = *(const short8*)(Ab + aoff[mi + 4]);
      aq[mi][1] = *(const short8*)(Ab + (aoff[mi + 4] ^ 64));
    }
    if (t + 1 < NT) STG(sB1, Bs[nb], 1, k1);
    __builtin_amdgcn_s_barrier();
    asm volatile("s_waitcnt lgkmcnt(0)" ::: "memory");
    __builtin_amdgcn_sched_barrier(0);
    __builtin_amdgcn_s_setprio(1);
#pragma unroll
    for (int mi = 0; mi < 4; mi++)
#pragma unroll
      for (int ni = 0; ni < 2; ni++)
#pragma unroll
        for (int kk = 0; kk < 2; kk++)
          acc[mi + 4][ni] = __builtin_amdgcn_mfma_f32_16x16x32_bf16(aq[mi][kk], bq[ni][kk], acc[mi + 4][ni], 0, 0, 0);
    __builtin_amdgcn_s_setprio(0);
    __builtin_amdgcn_s_barrier();

    // ---- phase 4: stage A0(t+2) into CURRENT buf half0 (reads done @p3); MFMA r1c1
    if (t + 2 < NT) STG(sA0, As[cb], 0, k2);
    __builtin_amdgcn_s_barrier();
    __builtin_amdgcn_s_setprio(1);
#pragma unroll
    for (int mi = 0; mi < 4; mi++)
#pragma unroll
      for (int ni = 2; ni < 4; ni++)
#pragma unroll
        for (int kk = 0; kk < 2; kk++)
          acc[mi + 4][ni] = __builtin_amdgcn_mfma_f32_16x16x32_bf16(aq[mi][kk], bq[ni][kk], acc[mi + 4][ni], 0, 0, 0);
    __builtin_amdgcn_s_setprio(0);
    if (t < NT - 2) {
      asm volatile("s_waitcnt vmcnt(2)" ::: "memory");
    } else if (t == NT - 2) {
      asm volatile("s_waitcnt vmcnt(0)" ::: "memory");
    }
    __builtin_amdgcn_sched_barrier(0);
    __builtin_amdgcn_s_barrier();
  }
#undef STG

  const size_t zoff = (size_t)blockIdx.z * zstride;
#pragma unroll
  for (int mi = 0; mi < 8; mi++) {
#pragma unroll
    for (int ni = 0; ni < 4; ni++) {
      int row0 = bm + wr * 128 + mi * 16 + lk * 4;
      int col = bn + wc * 64 + ni * 16 + lr;
#pragma unroll
      for (int r = 0; r < 4; r++) {
        float vv = acc[mi][ni][r];
        if (EPI == 0) {
          outb[(size_t)(row0 + r) * N + col] = f2bf(vv + bias[col]);
        } else if (EPI == 2) {
          float x = vv + bias[col];
          float y = 0.7978845608028654f * (x + 0.044715f * x * x * x);
          float th = 1.f - 2.f / (__expf(2.f * y) + 1.f);
          outb[(size_t)(row0 + r) * N + col] = f2bf(0.5f * x * (1.f + th));
        } else {
          outb[zoff + (size_t)(row0 + r) * N + col] = f2bf(vv);
        }
      }
    }
  }
}

// ---------- split-K reduce + gated residual (NS contiguous slices) ----------
template <int NS>
__global__ __launch_bounds__(256) void sk_epi(const unsigned short* __restrict__ pb,
                                              const float* __restrict__ bias,
                                              const float* __restrict__ addsrc,
                                              const float* __restrict__ gate,
                                              float* __restrict__ out) {
  const int N = 3072;
  const size_t MN = (size_t)2048 * 3072;
  int row = blockIdx.y;
  int col = blockIdx.x * 1024 + threadIdx.x * 4;
  size_t idx = (size_t)row * N + col;
  float4 a = *(const float4*)(addsrc + idx);
  float4 b = *(const float4*)(bias + col);
  float4 g = *(const float4*)(gate + col);
  float sum[4] = {b.x, b.y, b.z, b.w};
#pragma unroll
  for (int s = 0; s < NS; s++) {
    const unsigned short* p = pb + s * MN + idx;
#pragma unroll
    for (int i = 0; i < 4; i++) sum[i] += bf2f(p[i]);
  }
  float4 o;
  o.x = a.x + g.x * sum[0];
  o.y = a.y + g.y * sum[1];
  o.z = a.z + g.z * sum[2];
  o.w = a.w + g.w * sum[3];
  *(float4*)(out + idx) = o;
}

// ---------- qkv split-K reduce: bf16 out = p0 + p1 + bias (N=9216) ----------
__global__ __launch_bounds__(256) void sk_epiq(const unsigned short* __restrict__ p0,
                                               const unsigned short* __restrict__ p1,
                                               const float* __restrict__ bias,
                                               unsigned short* __restrict__ out) {
  const int N = 9216;
  int row = blockIdx.y;
  int col = blockIdx.x * 1024 + threadIdx.x * 4;
  size_t idx = (size_t)row * N + col;
#pragma unroll
  for (int i = 0; i < 4; i++)
    out[idx + i] = f2bf(bf2f(p0[idx + i]) + bf2f(p1[idx + i]) + bias[col + i]);
}

// ---------------- qkv post: rmsnorm + rope + K concat -----------------
__global__ __launch_bounds__(64) void qkv_post(const unsigned short* __restrict__ qkv,
                                               const float* __restrict__ k_txt,
                                               const float* __restrict__ cosb,
                                               const float* __restrict__ sinb,
                                               const float* __restrict__ qn,
                                               const float* __restrict__ kn,
                                               unsigned short* __restrict__ qb,
                                               unsigned short* __restrict__ kb) {
  int s = blockIdx.x, h = blockIdx.y;
  int lane = threadIdx.x;
  int d0 = lane * 2;
  if (s < 2048) {
    const unsigned short* rowp = qkv + (size_t)s * 9216;
    float c = cosb[s * 64 + lane], sn = sinb[s * 64 + lane];
    const float ascale = 0.08838834764831845f;  // 1/sqrt(128)
    {
      float a = bf2f(rowp[h * 128 + d0]), b = bf2f(rowp[h * 128 + d0 + 1]);
      float sq = a * a + b * b;
#pragma unroll
      for (int m = 32; m; m >>= 1) sq += __shfl_xor(sq, m);
      float rr = rsqrtf(sq * (1.f / 128.f) + 1e-6f);
      float x1 = a * rr * qn[d0], x2 = b * rr * qn[d0 + 1];
      float o1 = (x1 * c - x2 * sn) * ascale;
      float o2 = (x2 * c + x1 * sn) * ascale;
      size_t off = ((size_t)h * 2048 + s) * 128 + d0;
      qb[off] = f2bf(o1); qb[off + 1] = f2bf(o2);
    }
    {
      float a = bf2f(rowp[3072 + h * 128 + d0]), b = bf2f(rowp[3072 + h * 128 + d0 + 1]);
      float sq = a * a + b * b;
#pragma unroll
      for (int m = 32; m; m >>= 1) sq += __shfl_xor(sq, m);
      float rr = rsqrtf(sq * (1.f / 128.f) + 1e-6f);
      float x1 = a * rr * kn[d0], x2 = b * rr * kn[d0 + 1];
      float o1 = x1 * c - x2 * sn;
      float o2 = x2 * c + x1 * sn;
      size_t off = ((size_t)h * 2304 + s) * 128 + d0;
      kb[off] = f2bf(o1); kb[off + 1] = f2bf(o2);
    }
  } else {
    int t = s - 2048;
    size_t src = ((size_t)t * 24 + h) * 128 + d0;
    size_t off = ((size_t)h * 2304 + s) * 128 + d0;
    kb[off] = f2bf(k_txt[src]); kb[off + 1] = f2bf(k_txt[src + 1]);
  }
}

// ---------------- flash attention: 8 waves, 256 q/block (R13 version) -------
__global__ __launch_bounds__(512) void attn_k(const unsigned short* __restrict__ qb,
                                              const unsigned short* __restrict__ kb,
                                              const unsigned short* __restrict__ vt,
                                              unsigned short* __restrict__ out) {
  __shared__ unsigned short Ks[3][8192];
  __shared__ unsigned short Vs[3][8192];
  __shared__ unsigned short Ps[8][32 * 72];
  int h = blockIdx.y, q0 = blockIdx.x * 256;
  int tid = threadIdx.x, lane = tid & 63, w = tid >> 6;
  int lr = lane & 15, lk = lane >> 4;

  const unsigned short* kh = kb + (size_t)h * 2304 * 128;
  const unsigned short* vth = vt + (size_t)h * 128 * 2304;

  short8 qf[2][4];
#pragma unroll
  for (int mi = 0; mi < 2; mi++)
#pragma unroll
    for (int kf = 0; kf < 4; kf++)
      qf[mi][kf] = *(const short8*)&qb[((size_t)h * 2048 + q0 + w * 32 + mi * 16 + lr) * 128 + kf * 32 + lk * 8];

  const int kR0 = (tid * 16) >> 8, kR1 = (tid * 16 + 8192) >> 8;
  const int kCc = ((tid * 16) >> 4) & 15;
  const int kOf0 = kR0 * 128 + ((kCc ^ (kR0 & 15)) * 8);
  const int kOf1 = kR1 * 128 + ((kCc ^ (kR1 & 15)) * 8);
  const int vR0 = (tid * 16) >> 7, vR1 = (tid * 16 + 8192) >> 7;
  const int vCc = ((tid * 16) >> 4) & 7;
  const int vOf0 = vR0 * 2304 + ((vCc ^ (vR0 & 7)) * 8);
  const int vOf1 = vR1 * 2304 + ((vCc ^ (vR1 & 7)) * 8);

  float mrow[2][4], lsum[2][4];
#pragma unroll
  for (int mi = 0; mi < 2; mi++)
#pragma unroll
    for (int r = 0; r < 4; r++) { mrow[mi][r] = -1e30f; lsum[mi][r] = 0.f; }
  f32x4 oacc[2][8];
#pragma unroll
  for (int mi = 0; mi < 2; mi++)
#pragma unroll
    for (int i = 0; i < 8; i++) oacc[mi][i] = (f32x4){0.f, 0.f, 0.f, 0.f};

#pragma unroll
  for (int j = 0; j < 2; j++) {
    int kv = j * 64;
    load_lds16(kh + (size_t)kv * 128 + kOf0, (char*)Ks[j] + tid * 16);
    load_lds16(kh + (size_t)kv * 128 + kOf1, (char*)Ks[j] + tid * 16 + 8192);
    load_lds16(vth + kv + vOf0, (char*)Vs[j] + tid * 16);
    load_lds16(vth + kv + vOf1, (char*)Vs[j] + tid * 16 + 8192);
  }
  asm volatile("s_waitcnt vmcnt(4)" ::: "memory");
  __builtin_amdgcn_sched_barrier(0);
  __builtin_amdgcn_s_barrier();

  int cur = 0, st = 2;
  for (int kt = 0; kt < 36; kt++) {
    if (kt + 2 < 36) {
      int kv2 = (kt + 2) * 64;
      load_lds16(kh + (size_t)kv2 * 128 + kOf0, (char*)Ks[st] + tid * 16);
      load_lds16(kh + (size_t)kv2 * 128 + kOf1, (char*)Ks[st] + tid * 16 + 8192);
      load_lds16(vth + kv2 + vOf0, (char*)Vs[st] + tid * 16);
      load_lds16(vth + kv2 + vOf1, (char*)Vs[st] + tid * 16 + 8192);
    }

    f32x4 sa[2][4];
#pragma unroll
    for (int mi = 0; mi < 2; mi++)
#pragma unroll
      for (int ni = 0; ni < 4; ni++) sa[mi][ni] = (f32x4){0.f, 0.f, 0.f, 0.f};
    __builtin_amdgcn_s_setprio(1);
#pragma unroll
    for (int kf = 0; kf < 4; kf++) {
#pragma unroll
      for (int ni = 0; ni < 4; ni++) {
        int n = ni * 16 + lr;
        short8 bfr = *(const short8*)&Ks[cur][n * 128 + (((kf * 4 + lk) ^ lr) & 15) * 8];
        sa[0][ni] = __builtin_amdgcn_mfma_f32_16x16x32_bf16(qf[0][kf], bfr, sa[0][ni], 0, 0, 0);
        sa[1][ni] = __builtin_amdgcn_mfma_f32_16x16x32_bf16(qf[1][kf], bfr, sa[1][ni], 0, 0, 0);
      }
    }
    __builtin_amdgcn_s_setprio(0);

#pragma unroll
    for (int mi = 0; mi < 2; mi++) {
#pragma unroll
      for (int r = 0; r < 4; r++) {
        float mx = fmaxf(fmaxf(sa[mi][0][r], sa[mi][1][r]), fmaxf(sa[mi][2][r], sa[mi][3][r]));
#pragma unroll
        for (int m = 8; m; m >>= 1) mx = fmaxf(mx, __shfl_xor(mx, m));
        float mold = mrow[mi][r];
        if (mx > mold + 8.f) {
          float alpha = __expf(mold - mx);
          lsum[mi][r] *= alpha;
#pragma unroll
          for (int df = 0; df < 8; df++) oacc[mi][df][r] *= alpha;
          mrow[mi][r] = mx;
          mold = mx;
        }
        float p0 = __expf(sa[mi][0][r] - mold);
        float p1 = __expf(sa[mi][1][r] - mold);
        float p2 = __expf(sa[mi][2][r] - mold);
        float p3 = __expf(sa[mi][3][r] - mold);
        float su = p0 + p1 + p2 + p3;
#pragma unroll
        for (int m = 8; m; m >>= 1) su += __shfl_xor(su, m);
        lsum[mi][r] += su;
        int prow = (mi * 16 + lk * 4 + r) * 72;
        Ps[w][prow + 0 * 16 + lr] = f2bf(p0);
        Ps[w][prow + 1 * 16 + lr] = f2bf(p1);
        Ps[w][prow + 2 * 16 + lr] = f2bf(p2);
        Ps[w][prow + 3 * 16 + lr] = f2bf(p3);
      }
    }

    __builtin_amdgcn_s_setprio(1);
#pragma unroll
    for (int kf2 = 0; kf2 < 2; kf2++) {
      short8 pa0 = *(const short8*)&Ps[w][(0 * 16 + lr) * 72 + kf2 * 32 + lk * 8];
      short8 pa1 = *(const short8*)&Ps[w][(1 * 16 + lr) * 72 + kf2 * 32 + lk * 8];
#pragma unroll
      for (int df = 0; df < 8; df++) {
        int d = df * 16 + lr;
        short8 bv = *(const short8*)&Vs[cur][d * 64 + (((kf2 * 4 + lk) ^ (lr & 7)) & 7) * 8];
        oacc[0][df] = __builtin_amdgcn_mfma_f32_16x16x32_bf16(pa0, bv, oacc[0][df], 0, 0, 0);
        oacc[1][df] = __builtin_amdgcn_mfma_f32_16x16x32_bf16(pa1, bv, oacc[1][df], 0, 0, 0);
      }
    }
    __builtin_amdgcn_s_setprio(0);

    if (kt < 34) {
      asm volatile("s_waitcnt vmcnt(4)" ::: "memory");
    } else if (kt == 34) {
      asm volatile("s_waitcnt vmcnt(0)" ::: "memory");
    }
    __builtin_amdgcn_sched_barrier(0);
    __builtin_amdgcn_s_barrier();
    cur = (cur == 2) ? 0 : cur + 1;
    st = (st == 2) ? 0 : st + 1;
  }

#pragma unroll
  for (int mi = 0; mi < 2; mi++) {
#pragma unroll
    for (int r = 0; r < 4; r++) {
      float inv = 1.f / lsum[mi][r];
      int row = q0 + w * 32 + mi * 16 + lk * 4 + r;
#pragma unroll
      for (int df = 0; df < 8; df++)
        out[(size_t)row * 3072 + h * 128 + df * 16 + lr] = f2bf(oacc[mi][df][r] * inv);
    }
  }
}

// ---------------- launch -----------------
extern "C" void kernel_launch(void* const* d_in, const int* in_sizes, int n_in,
                              void* d_out, int out_size, void* d_ws, size_t ws_size,
                              hipStream_t stream) {
  const float* img = (const float*)d_in[0];
  const float* vec = (const float*)d_in[1];
  const float* cosb = (const float*)d_in[2];
  const float* sinb = (const float*)d_in[3];
  const float* k_txt = (const float*)d_in[4];
  const float* v_txt = (const float*)d_in[5];
  const float* mod_w = (const float*)d_in[6];
  const float* mod_b = (const float*)d_in[7];
  const float* qkv_w = (const float*)d_in[8];
  const float* qkv_b = (const float*)d_in[9];
  const float* qn_w = (const float*)d_in[10];
  const float* kn_w = (const float*)d_in[11];
  const float* proj_w = (const float*)d_in[12];
  const float* proj_b = (const float*)d_in[13];
  const float* mlp_w1 = (const float*)d_in[14];
  const float* mlp_b1 = (const float*)d_in[15];
  const float* mlp_w2 = (const float*)d_in[16];
  const float* mlp_b2 = (const float*)d_in[17];
  float* outp = (float*)d_out;

  const size_t MN = (size_t)2048 * 3072;
  char* ws = (char*)d_ws;
  unsigned short* qkvb = (unsigned short*)(ws + 0);           // [2048][9216] bf16
  unsigned short* qbuf = (unsigned short*)(ws + 37748736);    // [24][2048][128]
  unsigned short* kbuf = (unsigned short*)(ws + 50331648);    // [24][2304][128]
  unsigned short* vtbuf = (unsigned short*)(ws + 64487424);   // [24][128][2304] (V^T)
  unsigned short* attnb = (unsigned short*)(ws + 78643200);   // [2048][3072] bf16
  float* resid = (float*)(ws + 91226112);                     // [2048][3072] f32
  unsigned short* xln = (unsigned short*)(ws + 116391936);    // [2048][3072] bf16
  float* modv = (float*)(ws + 128974848);                     // [18432] f32
  unsigned short* wt = (unsigned short*)(ws + 129048576);     // up to [12288][3072] bf16
  unsigned short* hbuf = (unsigned short*)(ws + 0);           // [2048][12288] (reuses qkvb+qbuf)
  unsigned short* qp0 = (unsigned short*)(ws + 37748736);
  unsigned short* qp1 = (unsigned short*)(ws + 78643200);
  const size_t qzstride = (78643200 - 37748736) / 2;          // elems between slices
  unsigned short* pbuf = (unsigned short*)(ws + 50331648);

  // mod vector
  zero_mod<<<72, 256, 0, stream>>>(mod_b, modv);
  mod_gemv<<<dim3(72, 16), 256, 0, stream>>>(vec, mod_w, modv);

  // LN1 + modulate
  ln_kernel<<<2048, 256, 0, stream>>>(img, modv, 0, 3072, xln);

  // qkv GEMM, split-K=2 (576 blocks x 24 tiles of K=64)
  transpose_k<<<dim3(144, 48), 256, 0, stream>>>(qkv_w, wt, 3072, 9216);
  gemm8<3><<<dim3(36, 8, 2), 512, 0, stream>>>(xln, wt, nullptr, qp0, 9216, 3072, 1536, qzstride);
  sk_epiq<<<dim3(9, 2048), 256, 0, stream>>>(qp0, qp1, qkv_b, qkvb);

  // rmsnorm + rope + K concat; V transpose
  qkv_post<<<dim3(2304, 24), 64, 0, stream>>>(qkvb, k_txt, cosb, sinb, qn_w, kn_w, qbuf, kbuf);
  vt_k<<<dim3(144, 24), 256, 0, stream>>>(qkvb, v_txt, vtbuf);

  // attention
  attn_k<<<dim3(8, 24), 512, 0, stream>>>(qbuf, kbuf, vtbuf, attnb);

  // proj (split-K=2) + gated residual
  transpose_k<<<dim3(48, 48), 256, 0, stream>>>(proj_w, wt, 3072, 3072);
  gemm8<3><<<dim3(12, 8, 2), 512, 0, stream>>>(attnb, wt, nullptr, pbuf, 3072, 3072, 1536, MN);
  sk_epi<2><<<dim3(3, 2048), 256, 0, stream>>>(pbuf, proj_b, img, modv + 2 * 3072, resid);

  // LN2 + modulate
  ln_kernel<<<2048, 256, 0, stream>>>(resid, modv, 3 * 3072, 4 * 3072, xln);

  // mlp1 + gelu
  transpose_k<<<dim3(192, 48), 256, 0, stream>>>(mlp_w1, wt, 3072, 12288);
  gemm8<2><<<dim3(48, 8, 1), 512, 0, stream>>>(xln, wt, mlp_b1, hbuf, 12288, 3072, 3072, 0);

  // mlp2 (split-K=2) + gated residual -> out
  transpose_k<<<dim3(48, 192), 256, 0, stream>>>(mlp_w2, wt, 12288, 3072);
  gemm8<3><<<dim3(12, 8, 2), 512, 0, stream>>>(hbuf, wt, nullptr, pbuf, 3072, 12288, 6144, MN);
  sk_epi<2><<<dim3(3, 2048), 256, 0, stream>>>(pbuf, mlp_b2, resid, modv + 5 * 3072, outp);
}

// Round 15
// 938.082 us; speedup vs baseline: 1.0459x; 1.0459x over previous
//
#include <hip/hip_runtime.h>

typedef short short8 __attribute__((ext_vector_type(8)));
typedef float f32x4 __attribute__((ext_vector_type(4)));

#define DEV static __device__ __forceinline__

DEV unsigned short f2bf(float f) {
  union { float f; unsigned u; } v; v.f = f;
  unsigned u = v.u;
  unsigned r = u + 0x7fffu + ((u >> 16) & 1u);
  return (unsigned short)(r >> 16);
}
DEV float bf2f(unsigned short b) {
  union { unsigned u; float f; } v; v.u = ((unsigned)b) << 16;
  return v.f;
}
DEV void load_lds16(const void* g, void* l) {
  __builtin_amdgcn_global_load_lds(
      (const __attribute__((address_space(1))) unsigned int*)g,
      (__attribute__((address_space(3))) unsigned int*)l, 16, 0, 0);
}
// Bank swizzle for [row][64B] tiles, involution. Verified R3: 0 conflicts.
DEV int swz(int L) { return L ^ ((L >> 3) & 0x30); }

// ---------------- mod = silu(vec) @ mod_w + mod_b -----------------
__global__ __launch_bounds__(256) void zero_mod(const float* __restrict__ b, float* __restrict__ out) {
  int j = blockIdx.x * 256 + threadIdx.x;
  out[j] = b[j];
}

__global__ __launch_bounds__(256) void mod_gemv(const float* __restrict__ vec,
                                                const float* __restrict__ W,
                                                float* __restrict__ out) {
  __shared__ float sv[192];
  int tid = threadIdx.x;
  int kb = blockIdx.y * 192;
  if (tid < 192) {
    float x = vec[kb + tid];
    sv[tid] = x / (1.f + __expf(-x));
  }
  __syncthreads();
  int j = blockIdx.x * 256 + tid;
  float a0 = 0, a1 = 0, a2 = 0, a3 = 0;
  for (int i = 0; i < 192; i += 4) {
    a0 += sv[i + 0] * W[(size_t)(kb + i + 0) * 18432 + j];
    a1 += sv[i + 1] * W[(size_t)(kb + i + 1) * 18432 + j];
    a2 += sv[i + 2] * W[(size_t)(kb + i + 2) * 18432 + j];
    a3 += sv[i + 3] * W[(size_t)(kb + i + 3) * 18432 + j];
  }
  atomicAdd(&out[j], a0 + a1 + a2 + a3);
}

// ---------------- LayerNorm + modulate -> bf16 -----------------
__global__ __launch_bounds__(256) void ln_kernel(const float* __restrict__ in,
                                                 const float* __restrict__ mod,
                                                 int shift_off, int scale_off,
                                                 unsigned short* __restrict__ out) {
  int rowb = blockIdx.x;
  const float* x = in + (size_t)rowb * 3072;
  int tid = threadIdx.x;
  float s = 0.f, ss = 0.f;
  float4 v[3];
#pragma unroll
  for (int r = 0; r < 3; r++) {
    v[r] = *(const float4*)&x[r * 1024 + tid * 4];
    s += v[r].x + v[r].y + v[r].z + v[r].w;
    ss += v[r].x * v[r].x + v[r].y * v[r].y + v[r].z * v[r].z + v[r].w * v[r].w;
  }
#pragma unroll
  for (int m = 32; m; m >>= 1) { s += __shfl_xor(s, m); ss += __shfl_xor(ss, m); }
  __shared__ float red[8];
  int w = tid >> 6, lane = tid & 63;
  if (lane == 0) { red[w] = s; red[4 + w] = ss; }
  __syncthreads();
  s = red[0] + red[1] + red[2] + red[3];
  ss = red[4] + red[5] + red[6] + red[7];
  float mean = s * (1.f / 3072.f);
  float var = ss * (1.f / 3072.f) - mean * mean;
  float rstd = rsqrtf(var + 1e-6f);
#pragma unroll
  for (int r = 0; r < 3; r++) {
    int c = r * 1024 + tid * 4;
    float xv[4] = {v[r].x, v[r].y, v[r].z, v[r].w};
#pragma unroll
    for (int i = 0; i < 4; i++) {
      float o = (xv[i] - mean) * rstd * (1.f + mod[scale_off + c + i]) + mod[shift_off + c + i];
      out[(size_t)rowb * 3072 + c + i] = f2bf(o);
    }
  }
}

// ---------------- transpose fp32 [K][N] -> bf16 [N][K] -----------------
__global__ __launch_bounds__(256) void transpose_k(const float* __restrict__ src,
                                                   unsigned short* __restrict__ dst,
                                                   int K, int N) {
  __shared__ float t[64][65];
  int n0 = blockIdx.x * 64, k0 = blockIdx.y * 64;
  int tid = threadIdx.x;
#pragma unroll
  for (int i = 0; i < 16; i++) {
    int lin = i * 256 + tid;
    int r = lin >> 6, c = lin & 63;
    t[r][c] = src[(size_t)(k0 + r) * N + n0 + c];
  }
  __syncthreads();
#pragma unroll
  for (int i = 0; i < 16; i++) {
    int lin = i * 256 + tid;
    int rn = lin >> 6, cn = lin & 63;
    dst[(size_t)(n0 + rn) * K + k0 + cn] = f2bf(t[cn][rn]);
  }
}

// ---- V transpose (fused qkv split-K reduce): vt[h][128][2304] ----
__global__ __launch_bounds__(256) void vt_k(const unsigned short* __restrict__ p0,
                                            const unsigned short* __restrict__ p1,
                                            const float* __restrict__ qkv_b,
                                            const float* __restrict__ v_txt,
                                            unsigned short* __restrict__ vt) {
  int h = blockIdx.y;
  int c8 = blockIdx.x * 2 + (threadIdx.x >> 7);  // 0..287 kv-chunk
  int d = threadIdx.x & 127;
  int kvb = c8 * 8;
  short8 o;
  if (kvb < 2048) {
    float bias = qkv_b[6144 + h * 128 + d];
#pragma unroll
    for (int j = 0; j < 8; j++) {
      size_t idx = (size_t)(kvb + j) * 9216 + 6144 + h * 128 + d;
      o[j] = (short)f2bf(bf2f(p0[idx]) + bf2f(p1[idx]) + bias);
    }
  } else {
#pragma unroll
    for (int j = 0; j < 8; j++)
      o[j] = (short)f2bf(v_txt[((size_t)(kvb + j - 2048) * 24 + h) * 128 + d]);
  }
  *(short8*)&vt[((size_t)h * 128 + d) * 2304 + kvb] = o;
}

// ======== 256x256 GEMM, BK=32, ring-4 LDS, ONE barrier per K-tile ========
// (R6 core — best measured across 10 structural variants: 195us, MfmaUtil 34%.
// FROZEN.) EPI 0: bf16=acc+bias; EPI 2: gelu; EPI 3: partial=acc @ z*zstride.
template <int EPI>
__global__ __launch_bounds__(512, 2) void gemm8(const unsigned short* __restrict__ A,
                                                const unsigned short* __restrict__ Bt,
                                                const float* __restrict__ bias,
                                                unsigned short* __restrict__ outb,
                                                int N, int ldk, int klen, size_t zstride) {
  __shared__ unsigned short As[4][8192];  // ring of 4 K-tiles: [256 rows][32 k] swizzled
  __shared__ unsigned short Bs[4][8192];
  const int tid = threadIdx.x, lane = tid & 63, w = tid >> 6;
  const int wr = w >> 2, wc = w & 3;          // 2 x 4 waves
  const int lr = lane & 15, lk = lane >> 4;

  const int bm = blockIdx.y * 256, bn = blockIdx.x * 256;
  const int kbase = blockIdx.z * klen;
  const int NT = klen >> 5;

  const int D0 = tid * 16;          // rows 0..127 region
  const int D1 = 8192 + tid * 16;   // rows 128..255 region
  const int L0 = swz(D0), L1 = swz(D1);
  const unsigned short* sA0 = A + (size_t)(bm + (L0 >> 6)) * ldk + kbase + ((L0 & 63) >> 1);
  const unsigned short* sA1 = A + (size_t)(bm + (L1 >> 6)) * ldk + kbase + ((L1 & 63) >> 1);
  const unsigned short* sB0 = Bt + (size_t)(bn + (L0 >> 6)) * ldk + kbase + ((L0 & 63) >> 1);
  const unsigned short* sB1 = Bt + (size_t)(bn + (L1 >> 6)) * ldk + kbase + ((L1 & 63) >> 1);

  int aoff[8], boff[4];
#pragma unroll
  for (int mi = 0; mi < 8; mi++)
    aoff[mi] = swz(((wr * 128 + mi * 16 + lr) << 6) | (lk << 4));
#pragma unroll
  for (int ni = 0; ni < 4; ni++)
    boff[ni] = swz(((wc * 64 + ni * 16 + lr) << 6) | (lk << 4));

  f32x4 acc[8][4];
#pragma unroll
  for (int i = 0; i < 8; i++)
#pragma unroll
    for (int j = 0; j < 4; j++) acc[i][j] = (f32x4){0.f, 0.f, 0.f, 0.f};

#pragma unroll
  for (int j = 0; j < 3; j++) {
    load_lds16(sA0 + j * 32, (char*)As + j * 16384 + D0);
    load_lds16(sA1 + j * 32, (char*)As + j * 16384 + D1);
    load_lds16(sB0 + j * 32, (char*)Bs + j * 16384 + D0);
    load_lds16(sB1 + j * 32, (char*)Bs + j * 16384 + D1);
  }
  asm volatile("s_waitcnt vmcnt(8)" ::: "memory");
  __builtin_amdgcn_sched_barrier(0);
  __builtin_amdgcn_s_barrier();

  for (int t = 0; t < NT; ++t) {
    const int rt = t & 3;
    char* Ab = (char*)As + rt * 16384;
    char* Bb = (char*)Bs + rt * 16384;
    const int ss = (t + 3) & 3;
    const int sk = (t + 3) * 32;
    const bool stg = (t + 3) < NT;

    short8 af[8], bf[4];
#pragma unroll
    for (int mi = 0; mi < 8; mi++) af[mi] = *(const short8*)(Ab + aoff[mi]);
#pragma unroll
    for (int ni = 0; ni < 4; ni++) bf[ni] = *(const short8*)(Bb + boff[ni]);
    if (stg) {
      load_lds16(sA0 + sk, (char*)As + ss * 16384 + D0);
      load_lds16(sA1 + sk, (char*)As + ss * 16384 + D1);
      load_lds16(sB0 + sk, (char*)Bs + ss * 16384 + D0);
      load_lds16(sB1 + sk, (char*)Bs + ss * 16384 + D1);
    }
    __builtin_amdgcn_s_setprio(1);
#pragma unroll
    for (int mi = 0; mi < 8; mi++)
#pragma unroll
      for (int ni = 0; ni < 4; ni++)
        acc[mi][ni] = __builtin_amdgcn_mfma_f32_16x16x32_bf16(af[mi], bf[ni], acc[mi][ni], 0, 0, 0);
    __builtin_amdgcn_s_setprio(0);
    if (t < NT - 3) {
      asm volatile("s_waitcnt vmcnt(8)" ::: "memory");
    } else if (t == NT - 3) {
      asm volatile("s_waitcnt vmcnt(4)" ::: "memory");
    } else if (t == NT - 2) {
      asm volatile("s_waitcnt vmcnt(0)" ::: "memory");
    }
    __builtin_amdgcn_sched_barrier(0);
    __builtin_amdgcn_s_barrier();
  }

  const size_t zoff = (size_t)blockIdx.z * zstride;
#pragma unroll
  for (int mi = 0; mi < 8; mi++) {
#pragma unroll
    for (int ni = 0; ni < 4; ni++) {
      int row0 = bm + wr * 128 + mi * 16 + lk * 4;
      int col = bn + wc * 64 + ni * 16 + lr;
#pragma unroll
      for (int r = 0; r < 4; r++) {
        float vv = acc[mi][ni][r];
        if (EPI == 0) {
          outb[(size_t)(row0 + r) * N + col] = f2bf(vv + bias[col]);
        } else if (EPI == 2) {
          float x = vv + bias[col];
          float y = 0.7978845608028654f * (x + 0.044715f * x * x * x);
          float th = 1.f - 2.f / (__expf(2.f * y) + 1.f);
          outb[(size_t)(row0 + r) * N + col] = f2bf(0.5f * x * (1.f + th));
        } else {
          outb[zoff + (size_t)(row0 + r) * N + col] = f2bf(vv);
        }
      }
    }
  }
}

// ---------- split-K reduce + gated residual (NS contiguous slices) ----------
template <int NS>
__global__ __launch_bounds__(256) void sk_epi(const unsigned short* __restrict__ pb,
                                              const float* __restrict__ bias,
                                              const float* __restrict__ addsrc,
                                              const float* __restrict__ gate,
                                              float* __restrict__ out) {
  const int N = 3072;
  const size_t MN = (size_t)2048 * 3072;
  int row = blockIdx.y;
  int col = blockIdx.x * 1024 + threadIdx.x * 4;
  size_t idx = (size_t)row * N + col;
  float4 a = *(const float4*)(addsrc + idx);
  float4 b = *(const float4*)(bias + col);
  float4 g = *(const float4*)(gate + col);
  float sum[4] = {b.x, b.y, b.z, b.w};
#pragma unroll
  for (int s = 0; s < NS; s++) {
    const unsigned short* p = pb + s * MN + idx;
#pragma unroll
    for (int i = 0; i < 4; i++) sum[i] += bf2f(p[i]);
  }
  float4 o;
  o.x = a.x + g.x * sum[0];
  o.y = a.y + g.y * sum[1];
  o.z = a.z + g.z * sum[2];
  o.w = a.w + g.w * sum[3];
  *(float4*)(out + idx) = o;
}

// -------- qkv post (fused split-K reduce): rmsnorm + rope + K concat --------
__global__ __launch_bounds__(64) void qkv_post(const unsigned short* __restrict__ p0,
                                               const unsigned short* __restrict__ p1,
                                               const float* __restrict__ qkv_b,
                                               const float* __restrict__ k_txt,
                                               const float* __restrict__ cosb,
                                               const float* __restrict__ sinb,
                                               const float* __restrict__ qn,
                                               const float* __restrict__ kn,
                                               unsigned short* __restrict__ qb,
                                               unsigned short* __restrict__ kb) {
  int s = blockIdx.x, h = blockIdx.y;
  int lane = threadIdx.x;
  int d0 = lane * 2;
  if (s < 2048) {
    size_t rowb = (size_t)s * 9216;
    float c = cosb[s * 64 + lane], sn = sinb[s * 64 + lane];
    const float ascale = 0.08838834764831845f;  // 1/sqrt(128)
    {
      size_t i0 = rowb + h * 128 + d0;
      float a = bf2f(p0[i0]) + bf2f(p1[i0]) + qkv_b[h * 128 + d0];
      float b = bf2f(p0[i0 + 1]) + bf2f(p1[i0 + 1]) + qkv_b[h * 128 + d0 + 1];
      float sq = a * a + b * b;
#pragma unroll
      for (int m = 32; m; m >>= 1) sq += __shfl_xor(sq, m);
      float rr = rsqrtf(sq * (1.f / 128.f) + 1e-6f);
      float x1 = a * rr * qn[d0], x2 = b * rr * qn[d0 + 1];
      float o1 = (x1 * c - x2 * sn) * ascale;
      float o2 = (x2 * c + x1 * sn) * ascale;
      size_t off = ((size_t)h * 2048 + s) * 128 + d0;
      qb[off] = f2bf(o1); qb[off + 1] = f2bf(o2);
    }
    {
      size_t i0 = rowb + 3072 + h * 128 + d0;
      float a = bf2f(p0[i0]) + bf2f(p1[i0]) + qkv_b[3072 + h * 128 + d0];
      float b = bf2f(p0[i0 + 1]) + bf2f(p1[i0 + 1]) + qkv_b[3072 + h * 128 + d0 + 1];
      float sq = a * a + b * b;
#pragma unroll
      for (int m = 32; m; m >>= 1) sq += __shfl_xor(sq, m);
      float rr = rsqrtf(sq * (1.f / 128.f) + 1e-6f);
      float x1 = a * rr * kn[d0], x2 = b * rr * kn[d0 + 1];
      float o1 = x1 * c - x2 * sn;
      float o2 = x2 * c + x1 * sn;
      size_t off = ((size_t)h * 2304 + s) * 128 + d0;
      kb[off] = f2bf(o1); kb[off + 1] = f2bf(o2);
    }
  } else {
    int t = s - 2048;
    size_t src = ((size_t)t * 24 + h) * 128 + d0;
    size_t off = ((size_t)h * 2304 + s) * 128 + d0;
    kb[off] = f2bf(k_txt[src]); kb[off + 1] = f2bf(k_txt[src + 1]);
  }
}

// ---------------- flash attention: 8 waves, 256 q/block, dbuf K/Vt ----------
__global__ __launch_bounds__(512) void attn_k(const unsigned short* __restrict__ qb,
                                              const unsigned short* __restrict__ kb,
                                              const unsigned short* __restrict__ vt,
                                              unsigned short* __restrict__ out) {
  __shared__ unsigned short Ks[2][8192];
  __shared__ unsigned short Vs[2][8192];
  __shared__ unsigned short Ps[8][32 * 72];
  int h = blockIdx.y, q0 = blockIdx.x * 256;
  int tid = threadIdx.x, lane = tid & 63, w = tid >> 6;
  int lr = lane & 15, lk = lane >> 4;

  const unsigned short* kh = kb + (size_t)h * 2304 * 128;
  const unsigned short* vth = vt + (size_t)h * 128 * 2304;

  short8 qf[2][4];
#pragma unroll
  for (int mi = 0; mi < 2; mi++)
#pragma unroll
    for (int kf = 0; kf < 4; kf++)
      qf[mi][kf] = *(const short8*)&qb[((size_t)h * 2048 + q0 + w * 32 + mi * 16 + lr) * 128 + kf * 32 + lk * 8];

  const int kR0 = (tid * 16) >> 8, kR1 = (tid * 16 + 8192) >> 8;
  const int kCc = ((tid * 16) >> 4) & 15;
  const int kOf0 = kR0 * 128 + ((kCc ^ (kR0 & 15)) * 8);
  const int kOf1 = kR1 * 128 + ((kCc ^ (kR1 & 15)) * 8);
  const int vR0 = (tid * 16) >> 7, vR1 = (tid * 16 + 8192) >> 7;
  const int vCc = ((tid * 16) >> 4) & 7;
  const int vOf0 = vR0 * 2304 + ((vCc ^ (vR0 & 7)) * 8);
  const int vOf1 = vR1 * 2304 + ((vCc ^ (vR1 & 7)) * 8);

  float mrow[2][4], lsum[2][4];
#pragma unroll
  for (int mi = 0; mi < 2; mi++)
#pragma unroll
    for (int r = 0; r < 4; r++) { mrow[mi][r] = -1e30f; lsum[mi][r] = 0.f; }
  f32x4 oacc[2][8];
#pragma unroll
  for (int mi = 0; mi < 2; mi++)
#pragma unroll
    for (int i = 0; i < 8; i++) oacc[mi][i] = (f32x4){0.f, 0.f, 0.f, 0.f};

  load_lds16(kh + kOf0, (char*)Ks[0] + tid * 16);
  load_lds16(kh + kOf1, (char*)Ks[0] + tid * 16 + 8192);
  load_lds16(vth + vOf0, (char*)Vs[0] + tid * 16);
  load_lds16(vth + vOf1, (char*)Vs[0] + tid * 16 + 8192);
  asm volatile("s_waitcnt vmcnt(0)" ::: "memory");
  __builtin_amdgcn_sched_barrier(0);
  __builtin_amdgcn_s_barrier();

  for (int kt = 0; kt < 36; kt++) {
    const int cur = kt & 1, nxt = cur ^ 1;
    if (kt + 1 < 36) {
      int kv1 = (kt + 1) * 64;
      load_lds16(kh + (size_t)kv1 * 128 + kOf0, (char*)Ks[nxt] + tid * 16);
      load_lds16(kh + (size_t)kv1 * 128 + kOf1, (char*)Ks[nxt] + tid * 16 + 8192);
      load_lds16(vth + kv1 + vOf0, (char*)Vs[nxt] + tid * 16);
      load_lds16(vth + kv1 + vOf1, (char*)Vs[nxt] + tid * 16 + 8192);
    }

    f32x4 sa[2][4];
#pragma unroll
    for (int mi = 0; mi < 2; mi++)
#pragma unroll
      for (int ni = 0; ni < 4; ni++) sa[mi][ni] = (f32x4){0.f, 0.f, 0.f, 0.f};
    __builtin_amdgcn_s_setprio(1);
#pragma unroll
    for (int kf = 0; kf < 4; kf++) {
#pragma unroll
      for (int ni = 0; ni < 4; ni++) {
        int n = ni * 16 + lr;
        short8 bfr = *(const short8*)&Ks[cur][n * 128 + (((kf * 4 + lk) ^ lr) & 15) * 8];
        sa[0][ni] = __builtin_amdgcn_mfma_f32_16x16x32_bf16(qf[0][kf], bfr, sa[0][ni], 0, 0, 0);
        sa[1][ni] = __builtin_amdgcn_mfma_f32_16x16x32_bf16(qf[1][kf], bfr, sa[1][ni], 0, 0, 0);
      }
    }
    __builtin_amdgcn_s_setprio(0);

#pragma unroll
    for (int mi = 0; mi < 2; mi++) {
#pragma unroll
      for (int r = 0; r < 4; r++) {
        float mx = fmaxf(fmaxf(sa[mi][0][r], sa[mi][1][r]), fmaxf(sa[mi][2][r], sa[mi][3][r]));
#pragma unroll
        for (int m = 8; m; m >>= 1) mx = fmaxf(mx, __shfl_xor(mx, m));
        float mnew = fmaxf(mrow[mi][r], mx);
        float p0 = __expf(sa[mi][0][r] - mnew);
        float p1 = __expf(sa[mi][1][r] - mnew);
        float p2 = __expf(sa[mi][2][r] - mnew);
        float p3 = __expf(sa[mi][3][r] - mnew);
        float su = p0 + p1 + p2 + p3;
#pragma unroll
        for (int m = 8; m; m >>= 1) su += __shfl_xor(su, m);
        float alpha = __expf(mrow[mi][r] - mnew);
        lsum[mi][r] = lsum[mi][r] * alpha + su;
        mrow[mi][r] = mnew;
#pragma unroll
        for (int df = 0; df < 8; df++) oacc[mi][df][r] *= alpha;
        int prow = (mi * 16 + lk * 4 + r) * 72;
        Ps[w][prow + 0 * 16 + lr] = f2bf(p0);
        Ps[w][prow + 1 * 16 + lr] = f2bf(p1);
        Ps[w][prow + 2 * 16 + lr] = f2bf(p2);
        Ps[w][prow + 3 * 16 + lr] = f2bf(p3);
      }
    }

    __builtin_amdgcn_s_setprio(1);
#pragma unroll
    for (int kf2 = 0; kf2 < 2; kf2++) {
      short8 pa0 = *(const short8*)&Ps[w][(0 * 16 + lr) * 72 + kf2 * 32 + lk * 8];
      short8 pa1 = *(const short8*)&Ps[w][(1 * 16 + lr) * 72 + kf2 * 32 + lk * 8];
#pragma unroll
      for (int df = 0; df < 8; df++) {
        int d = df * 16 + lr;
        short8 bv = *(const short8*)&Vs[cur][d * 64 + (((kf2 * 4 + lk) ^ (lr & 7)) & 7) * 8];
        oacc[0][df] = __builtin_amdgcn_mfma_f32_16x16x32_bf16(pa0, bv, oacc[0][df], 0, 0, 0);
        oacc[1][df] = __builtin_amdgcn_mfma_f32_16x16x32_bf16(pa1, bv, oacc[1][df], 0, 0, 0);
      }
    }
    __builtin_amdgcn_s_setprio(0);

    asm volatile("s_waitcnt vmcnt(0)" ::: "memory");
    __builtin_amdgcn_sched_barrier(0);
    __builtin_amdgcn_s_barrier();
  }

#pragma unroll
  for (int mi = 0; mi < 2; mi++) {
#pragma unroll
    for (int r = 0; r < 4; r++) {
      float inv = 1.f / lsum[mi][r];
      int row = q0 + w * 32 + mi * 16 + lk * 4 + r;
#pragma unroll
      for (int df = 0; df < 8; df++)
        out[(size_t)row * 3072 + h * 128 + df * 16 + lr] = f2bf(oacc[mi][df][r] * inv);
    }
  }
}

// ---------------- launch -----------------
// WS layout / timeline (all transitions audited):
//   qbuf   @0          (12.58M)  written by qkv_post, read by attn
//   kbuf   @12582912   (14.16M)  written by qkv_post, read by attn
//   vtbuf  @26738688   (14.16M)  written by vt_k, read by attn (ends @qp0)
//   qp0    @40894464   (37.75M)  qkv partial z=0 (consumed by qkv_post/vt_k)
//   qp1    @78643200   (37.75M)  qkv partial z=1 (dead before attnb write)
//   pbuf   @50331648   (25.17M)  proj/mlp2 partials (over dead qp0 middle)
//   attnb  @78643200   (12.58M)  attn out (over dead qp1)
//   resid  @91226112   (25.17M f32)
//   xln    @116391936  (12.58M)
//   modv   @128974848  (72K)
//   wt     @129048576  (75.5M)
//   hbuf   @0          (50.33M)  mlp hidden (over dead qbuf/kbuf/vtbuf)
extern "C" void kernel_launch(void* const* d_in, const int* in_sizes, int n_in,
                              void* d_out, int out_size, void* d_ws, size_t ws_size,
                              hipStream_t stream) {
  const float* img = (const float*)d_in[0];
  const float* vec = (const float*)d_in[1];
  const float* cosb = (const float*)d_in[2];
  const float* sinb = (const float*)d_in[3];
  const float* k_txt = (const float*)d_in[4];
  const float* v_txt = (const float*)d_in[5];
  const float* mod_w = (const float*)d_in[6];
  const float* mod_b = (const float*)d_in[7];
  const float* qkv_w = (const float*)d_in[8];
  const float* qkv_b = (const float*)d_in[9];
  const float* qn_w = (const float*)d_in[10];
  const float* kn_w = (const float*)d_in[11];
  const float* proj_w = (const float*)d_in[12];
  const float* proj_b = (const float*)d_in[13];
  const float* mlp_w1 = (const float*)d_in[14];
  const float* mlp_b1 = (const float*)d_in[15];
  const float* mlp_w2 = (const float*)d_in[16];
  const float* mlp_b2 = (const float*)d_in[17];
  float* outp = (float*)d_out;

  const size_t MN = (size_t)2048 * 3072;
  char* ws = (char*)d_ws;
  unsigned short* qbuf = (unsigned short*)(ws + 0);           // [24][2048][128]
  unsigned short* kbuf = (unsigned short*)(ws + 12582912);    // [24][2304][128]
  unsigned short* vtbuf = (unsigned short*)(ws + 26738688);   // [24][128][2304] (V^T)
  unsigned short* qp0 = (unsigned short*)(ws + 40894464);     // qkv partial z=0
  unsigned short* qp1 = (unsigned short*)(ws + 78643200);     // qkv partial z=1
  const size_t qzstride = (78643200 - 40894464) / 2;          // 18874368 elems
  unsigned short* pbuf = (unsigned short*)(ws + 50331648);    // proj/mlp2 partials
  unsigned short* attnb = (unsigned short*)(ws + 78643200);   // [2048][3072] bf16
  float* resid = (float*)(ws + 91226112);                     // [2048][3072] f32
  unsigned short* xln = (unsigned short*)(ws + 116391936);    // [2048][3072] bf16
  float* modv = (float*)(ws + 128974848);                     // [18432] f32
  unsigned short* wt = (unsigned short*)(ws + 129048576);     // up to [12288][3072]
  unsigned short* hbuf = (unsigned short*)(ws + 0);           // [2048][12288]

  // mod vector
  zero_mod<<<72, 256, 0, stream>>>(mod_b, modv);
  mod_gemv<<<dim3(72, 16), 256, 0, stream>>>(vec, mod_w, modv);

  // LN1 + modulate
  ln_kernel<<<2048, 256, 0, stream>>>(img, modv, 0, 3072, xln);

  // qkv GEMM, split-K=2 (576 blocks x 48 tiles); reduce fused into consumers
  transpose_k<<<dim3(144, 48), 256, 0, stream>>>(qkv_w, wt, 3072, 9216);
  gemm8<3><<<dim3(36, 8, 2), 512, 0, stream>>>(xln, wt, nullptr, qp0, 9216, 3072, 1536, qzstride);

  // rmsnorm + rope + K concat; V transpose (both read qp0+qp1+bias directly)
  qkv_post<<<dim3(2304, 24), 64, 0, stream>>>(qp0, qp1, qkv_b, k_txt, cosb, sinb,
                                              qn_w, kn_w, qbuf, kbuf);
  vt_k<<<dim3(144, 24), 256, 0, stream>>>(qp0, qp1, qkv_b, v_txt, vtbuf);

  // attention
  attn_k<<<dim3(8, 24), 512, 0, stream>>>(qbuf, kbuf, vtbuf, attnb);

  // proj (split-K=2) + gated residual
  transpose_k<<<dim3(48, 48), 256, 0, stream>>>(proj_w, wt, 3072, 3072);
  gemm8<3><<<dim3(12, 8, 2), 512, 0, stream>>>(attnb, wt, nullptr, pbuf, 3072, 3072, 1536, MN);
  sk_epi<2><<<dim3(3, 2048), 256, 0, stream>>>(pbuf, proj_b, img, modv + 2 * 3072, resid);

  // LN2 + modulate
  ln_kernel<<<2048, 256, 0, stream>>>(resid, modv, 3 * 3072, 4 * 3072, xln);

  // mlp1 + gelu
  transpose_k<<<dim3(192, 48), 256, 0, stream>>>(mlp_w1, wt, 3072, 12288);
  gemm8<2><<<dim3(48, 8, 1), 512, 0, stream>>>(xln, wt, mlp_b1, hbuf, 12288, 3072, 3072, 0);

  // mlp2 (split-K=2) + gated residual -> out
  transpose_k<<<dim3(48, 192), 256, 0, stream>>>(mlp_w2, wt, 12288, 3072);
  gemm8<3><<<dim3(12, 8, 2), 512, 0, stream>>>(hbuf, wt, nullptr, pbuf, 3072, 12288, 6144, MN);
  sk_epi<2><<<dim3(3, 2048), 256, 0, stream>>>(pbuf, mlp_b2, resid, modv + 5 * 3072, outp);
}